// Round 2
// baseline (575.912 us; speedup 1.0000x reference)
//
#include <hip/hip_runtime.h>
#include <cstddef>

// Problem: B=4, C=256, H=W=128, HW=16384, NPIX=65536
#define EPS_ 1e-5f

// ---------------------------------------------------------------------------
// Kernel 1: per-batch GEMM, CHANNEL-major output:
//   f1[((b*256 + o) * 16384) + p] = sum_c x[b,c,p] * W1[o,c] + b1[o]
// Tile: 128 pixels x 64 outs per block, K-chunk 32. 256 threads,
// thread = 4 contiguous px x 8 contiguous o = 32 fp32 accumulators.
// ---------------------------------------------------------------------------
__global__ __launch_bounds__(256) void k_gemm(const float* __restrict__ x,
                                              const float* __restrict__ W1,
                                              const float* __restrict__ b1,
                                              float* __restrict__ f1)
{
  __shared__ float xs[32][128];   // [k][p]
  __shared__ float wsh[32][68];   // [k][o], padded 64->68 keeps rows 16B aligned
  const int t  = threadIdx.x;
  const int tx = t & 31, ty = t >> 5;
  const int pbase = blockIdx.x * 128;
  const int o0    = blockIdx.y * 64;
  const int b     = blockIdx.z;
  const float* xb = x + (size_t)b * 256 * 16384;

  float acc[4][8];
#pragma unroll
  for (int i = 0; i < 4; ++i)
#pragma unroll
    for (int j = 0; j < 8; ++j) acc[i][j] = 0.f;

  for (int c0 = 0; c0 < 256; c0 += 32) {
    {
      const int row = t >> 3;
      const int f4  = t & 7;
#pragma unroll
      for (int jj = 0; jj < 4; ++jj) {
        const int col = (f4 + jj * 8) * 4;
        *(float4*)&xs[row][col] =
            *(const float4*)(xb + (size_t)(c0 + row) * 16384 + pbase + col);
      }
    }
    {
      const int o_l = t >> 2;
      const int cc  = (t & 3) * 8;
      float4 v0 = *(const float4*)(W1 + (size_t)(o0 + o_l) * 256 + c0 + cc);
      float4 v1 = *(const float4*)(W1 + (size_t)(o0 + o_l) * 256 + c0 + cc + 4);
      wsh[cc + 0][o_l] = v0.x; wsh[cc + 1][o_l] = v0.y;
      wsh[cc + 2][o_l] = v0.z; wsh[cc + 3][o_l] = v0.w;
      wsh[cc + 4][o_l] = v1.x; wsh[cc + 5][o_l] = v1.y;
      wsh[cc + 6][o_l] = v1.z; wsh[cc + 7][o_l] = v1.w;
    }
    __syncthreads();
#pragma unroll 8
    for (int kk = 0; kk < 32; ++kk) {
      float xv[4], wv[8];
      *(float4*)&xv[0] = *(const float4*)&xs[kk][tx * 4];
      *(float4*)&wv[0] = *(const float4*)&wsh[kk][ty * 8];
      *(float4*)&wv[4] = *(const float4*)&wsh[kk][ty * 8 + 4];
#pragma unroll
      for (int i = 0; i < 4; ++i)
#pragma unroll
        for (int j = 0; j < 8; ++j) acc[i][j] = fmaf(xv[i], wv[j], acc[i][j]);
    }
    __syncthreads();
  }

#pragma unroll
  for (int j = 0; j < 8; ++j) {
    const int o = o0 + ty * 8 + j;
    const float bb = b1[o];
    float4 v;
    v.x = acc[0][j] + bb; v.y = acc[1][j] + bb;
    v.z = acc[2][j] + bb; v.w = acc[3][j] + bb;
    *(float4*)(f1 + ((size_t)(b * 256 + o)) * 16384 + pbase + tx * 4) = v;
  }
}

// ---------------------------------------------------------------------------
// Kernel 2: partial L1 distances, channel-major with spatial tiling.
// Block: 256 thr = 8 rows x 128 w tile (4 px/thread), loops 32 channels.
// Per channel: stage rows h0-1..h0+8 (10x128 = 5KB) in LDS, aligned b128
// reads with edge-clamp fixup, accumulate |c - nbr| into 32 registers.
// End: atomicAdd partials into dist[p][8].
// Grid: (16 htiles, 4 b, 8 c-chunks) = 512 blocks.
// ---------------------------------------------------------------------------
__global__ __launch_bounds__(256) void k_dist(const float* __restrict__ f1,
                                              float* __restrict__ dist)
{
  __shared__ float4 lds4[320];    // [10 rows][32 float4]
  const int t  = threadIdx.x;
  const int h0 = blockIdx.x * 8;
  const int b  = blockIdx.y;
  const int c0 = blockIdx.z * 32;
  const int r  = t >> 5;          // 0..7 (tile row)
  const int cq = t & 31;          // float4 column
  const float* plane0 = f1 + ((size_t)(b * 256 + c0)) * 16384;

  float acc[4][8];
#pragma unroll
  for (int i = 0; i < 4; ++i)
#pragma unroll
    for (int k = 0; k < 8; ++k) acc[i][k] = 0.f;

  for (int cc = 0; cc < 32; ++cc) {
    const float* pl = plane0 + (size_t)cc * 16384;
    __syncthreads();
    for (int idx = t; idx < 320; idx += 256) {
      int sh = h0 - 1 + (idx >> 5);
      sh = sh < 0 ? 0 : (sh > 127 ? 127 : sh);
      lds4[idx] = *(const float4*)(pl + sh * 128 + (idx & 31) * 4);
    }
    __syncthreads();

    float vals[3][6];
#pragma unroll
    for (int d = 0; d < 3; ++d) {
      const float4* rowp = lds4 + (r + d) * 32;   // lds row r+d
      float4 c  = rowp[cq];
      float4 lf = rowp[cq == 0 ? 0 : cq - 1];
      float4 rg = rowp[cq == 31 ? 31 : cq + 1];
      vals[d][0] = (cq == 0)  ? c.x : lf.w;
      vals[d][1] = c.x; vals[d][2] = c.y; vals[d][3] = c.z; vals[d][4] = c.w;
      vals[d][5] = (cq == 31) ? c.w : rg.x;
    }
#pragma unroll
    for (int i = 0; i < 4; ++i) {
      const float cv = vals[1][i + 1];
      acc[i][0] += fabsf(cv - vals[0][i]);
      acc[i][1] += fabsf(cv - vals[0][i + 1]);
      acc[i][2] += fabsf(cv - vals[0][i + 2]);
      acc[i][3] += fabsf(cv - vals[1][i]);
      acc[i][4] += fabsf(cv - vals[1][i + 2]);
      acc[i][5] += fabsf(cv - vals[2][i]);
      acc[i][6] += fabsf(cv - vals[2][i + 1]);
      acc[i][7] += fabsf(cv - vals[2][i + 2]);
    }
  }

  const int p = (b << 14) + (h0 + r) * 128 + cq * 4;
#pragma unroll
  for (int i = 0; i < 4; ++i)
#pragma unroll
    for (int k = 0; k < 8; ++k)
      atomicAdd(&dist[(size_t)(p + i) * 8 + k], acc[i][k]);
}

// ---------------------------------------------------------------------------
// Kernel 3: softmax(-r*dist) per pixel (held in regs), weighted neighbor
// aggregation + residual, write pre-BN tensor channel-major, fused BN-stat
// accumulation (wave butterfly -> 1 atomic pair per wave per channel).
// Same tiling as k_dist.
// ---------------------------------------------------------------------------
__global__ __launch_bounds__(256) void k_agg2(const float* __restrict__ f1,
                                              const float* __restrict__ x,
                                              const float* __restrict__ dist,
                                              const float* __restrict__ rp,
                                              float* __restrict__ bn_in,
                                              float* __restrict__ s1,
                                              float* __restrict__ s2)
{
  __shared__ float4 lds4[320];
  const int t  = threadIdx.x;
  const int h0 = blockIdx.x * 8;
  const int b  = blockIdx.y;
  const int c0 = blockIdx.z * 32;
  const int r  = t >> 5;
  const int cq = t & 31;
  const int p  = (b << 14) + (h0 + r) * 128 + cq * 4;
  const float rv = rp[0];

  // softmax weights for this thread's 4 pixels
  float m[4][8];
#pragma unroll
  for (int i = 0; i < 4; ++i) {
    float4 d0 = *(const float4*)(dist + (size_t)(p + i) * 8);
    float4 d1 = *(const float4*)(dist + (size_t)(p + i) * 8 + 4);
    float lg[8] = {-rv * d0.x, -rv * d0.y, -rv * d0.z, -rv * d0.w,
                   -rv * d1.x, -rv * d1.y, -rv * d1.z, -rv * d1.w};
    float mx = lg[0];
#pragma unroll
    for (int k = 1; k < 8; ++k) mx = fmaxf(mx, lg[k]);
    float sm = 0.f;
#pragma unroll
    for (int k = 0; k < 8; ++k) { lg[k] = __expf(lg[k] - mx); sm += lg[k]; }
    const float inv = 1.f / sm;
#pragma unroll
    for (int k = 0; k < 8; ++k) m[i][k] = lg[k] * inv;
  }

  const float* plane0 = f1 + ((size_t)(b * 256 + c0)) * 16384;
  for (int cc = 0; cc < 32; ++cc) {
    const float* pl = plane0 + (size_t)cc * 16384;
    __syncthreads();
    for (int idx = t; idx < 320; idx += 256) {
      int sh = h0 - 1 + (idx >> 5);
      sh = sh < 0 ? 0 : (sh > 127 ? 127 : sh);
      lds4[idx] = *(const float4*)(pl + sh * 128 + (idx & 31) * 4);
    }
    __syncthreads();

    float vals[3][6];
#pragma unroll
    for (int d = 0; d < 3; ++d) {
      const float4* rowp = lds4 + (r + d) * 32;
      float4 c  = rowp[cq];
      float4 lf = rowp[cq == 0 ? 0 : cq - 1];
      float4 rg = rowp[cq == 31 ? 31 : cq + 1];
      vals[d][0] = (cq == 0)  ? c.x : lf.w;
      vals[d][1] = c.x; vals[d][2] = c.y; vals[d][3] = c.z; vals[d][4] = c.w;
      vals[d][5] = (cq == 31) ? c.w : rg.x;
    }

    const size_t chanoff = ((size_t)(b * 256 + c0 + cc)) * 16384 +
                           (size_t)(h0 + r) * 128 + cq * 4;
    const float4 xv = *(const float4*)(x + chanoff);
    float o_[4] = {xv.x, xv.y, xv.z, xv.w};
#pragma unroll
    for (int i = 0; i < 4; ++i) {
      o_[i] = fmaf(m[i][0], vals[0][i],     o_[i]);
      o_[i] = fmaf(m[i][1], vals[0][i + 1], o_[i]);
      o_[i] = fmaf(m[i][2], vals[0][i + 2], o_[i]);
      o_[i] = fmaf(m[i][3], vals[1][i],     o_[i]);
      o_[i] = fmaf(m[i][4], vals[1][i + 2], o_[i]);
      o_[i] = fmaf(m[i][5], vals[2][i],     o_[i]);
      o_[i] = fmaf(m[i][6], vals[2][i + 1], o_[i]);
      o_[i] = fmaf(m[i][7], vals[2][i + 2], o_[i]);
    }
    float4 ov; ov.x = o_[0]; ov.y = o_[1]; ov.z = o_[2]; ov.w = o_[3];
    *(float4*)(bn_in + chanoff) = ov;

    // BN stats: wave butterfly, then one atomic pair per wave
    float s = o_[0] + o_[1] + o_[2] + o_[3];
    float q = o_[0] * o_[0] + o_[1] * o_[1] + o_[2] * o_[2] + o_[3] * o_[3];
#pragma unroll
    for (int msk = 1; msk < 64; msk <<= 1) {
      s += __shfl_xor(s, msk, 64);
      q += __shfl_xor(q, msk, 64);
    }
    if ((t & 63) == 0) {
      atomicAdd(&s1[c0 + cc], s);
      atomicAdd(&s2[c0 + cc], q);
    }
  }
}

// ---------------------------------------------------------------------------
// Kernel 4: per-channel BN folds: scale = gamma*rsqrt(var+eps),
//           shift = beta - mean*scale   (biased var, N = 65536)
// ---------------------------------------------------------------------------
__global__ void k_stats(const float* __restrict__ s1, const float* __restrict__ s2,
                        const float* __restrict__ gamma, const float* __restrict__ beta,
                        float* __restrict__ scale, float* __restrict__ shift)
{
  const int c = threadIdx.x;
  const float n = 65536.f;
  const float mean = s1[c] / n;
  const float var  = s2[c] / n - mean * mean;
  const float sc   = gamma[c] * rsqrtf(var + EPS_);
  scale[c] = sc;
  shift[c] = beta[c] - mean * sc;
}

// ---------------------------------------------------------------------------
// Kernel 5: elementwise BN affine + LeakyReLU (channel-major, no transpose).
// ---------------------------------------------------------------------------
__global__ __launch_bounds__(256) void k_apply(const float* __restrict__ bn_in,
                                               const float* __restrict__ scale,
                                               const float* __restrict__ shift,
                                               float* __restrict__ out)
{
  const int base = blockIdx.x * 1024 + threadIdx.x;   // float4 index
#pragma unroll
  for (int j = 0; j < 4; ++j) {
    const int idx = base + j * 256;
    const int c   = (idx >> 12) & 255;               // elem>>14 == idx>>12
    const float sc = scale[c], sh = shift[c];
    const float4 v = *(const float4*)(bn_in + (size_t)idx * 4);
    float4 o;
    float u;
    u = fmaf(v.x, sc, sh); o.x = u > 0.f ? u : 0.01f * u;
    u = fmaf(v.y, sc, sh); o.y = u > 0.f ? u : 0.01f * u;
    u = fmaf(v.z, sc, sh); o.z = u > 0.f ? u : 0.01f * u;
    u = fmaf(v.w, sc, sh); o.w = u > 0.f ? u : 0.01f * u;
    *(float4*)(out + (size_t)idx * 4) = o;
  }
}

// ---------------------------------------------------------------------------
// Workspace: f1 64MB | bn_in 64MB | dist 2MB | s1/s2/scale/shift 4KB
// ---------------------------------------------------------------------------
extern "C" void kernel_launch(void* const* d_in, const int* in_sizes, int n_in,
                              void* d_out, int out_size, void* d_ws, size_t ws_size,
                              hipStream_t stream)
{
  const float* x     = (const float*)d_in[0];
  const float* W1    = (const float*)d_in[1];
  const float* b1    = (const float*)d_in[2];
  const float* r     = (const float*)d_in[3];
  const float* gamma = (const float*)d_in[4];
  const float* beta  = (const float*)d_in[5];
  float* out = (float*)d_out;

  char* ws = (char*)d_ws;
  float* f1    = (float*)ws;                           // 64 MB
  float* bn_in = (float*)(ws + ((size_t)64 << 20));    // 64 MB
  float* dist  = (float*)(ws + ((size_t)128 << 20));   // 2 MB
  float* s1    = dist + 524288;
  float* s2    = s1 + 256;
  float* scale = s1 + 512;
  float* shift = s1 + 768;

  // zero dist + s1 + s2 (contiguous): 2 MB + 2 KB
  hipMemsetAsync(dist, 0, 524288 * sizeof(float) + 512 * sizeof(float), stream);

  k_gemm <<<dim3(128, 4, 4), 256, 0, stream>>>(x, W1, b1, f1);
  k_dist <<<dim3(16, 4, 8),  256, 0, stream>>>(f1, dist);
  k_agg2 <<<dim3(16, 4, 8),  256, 0, stream>>>(f1, x, dist, r, bn_in, s1, s2);
  k_stats<<<dim3(1),         256, 0, stream>>>(s1, s2, gamma, beta, scale, shift);
  k_apply<<<dim3(4096),      256, 0, stream>>>(bn_in, scale, shift, out);
}

// Round 3
// 563.794 us; speedup vs baseline: 1.0215x; 1.0215x over previous
//
#include <hip/hip_runtime.h>
#include <cstddef>

// Problem: B=4, C=256, H=W=128, HW=16384, NPIX=65536
#define EPS_ 1e-5f

// ---------------------------------------------------------------------------
// Kernel 1: per-batch GEMM, CHANNEL-major output:
//   f1[((b*256 + o) * 16384) + p] = sum_c x[b,c,p] * W1[o,c] + b1[o]
// Tile: 128 pixels x 64 outs per block, K-chunk 32. 256 threads,
// thread = 4 contiguous px x 8 contiguous o = 32 fp32 accumulators.
// ---------------------------------------------------------------------------
__global__ __launch_bounds__(256) void k_gemm(const float* __restrict__ x,
                                              const float* __restrict__ W1,
                                              const float* __restrict__ b1,
                                              float* __restrict__ f1)
{
  __shared__ float xs[32][128];   // [k][p]
  __shared__ float wsh[32][68];   // [k][o], padded 64->68 keeps rows 16B aligned
  const int t  = threadIdx.x;
  const int tx = t & 31, ty = t >> 5;
  const int pbase = blockIdx.x * 128;
  const int o0    = blockIdx.y * 64;
  const int b     = blockIdx.z;
  const float* xb = x + (size_t)b * 256 * 16384;

  float acc[4][8];
#pragma unroll
  for (int i = 0; i < 4; ++i)
#pragma unroll
    for (int j = 0; j < 8; ++j) acc[i][j] = 0.f;

  for (int c0 = 0; c0 < 256; c0 += 32) {
    {
      const int row = t >> 3;
      const int f4  = t & 7;
#pragma unroll
      for (int jj = 0; jj < 4; ++jj) {
        const int col = (f4 + jj * 8) * 4;
        *(float4*)&xs[row][col] =
            *(const float4*)(xb + (size_t)(c0 + row) * 16384 + pbase + col);
      }
    }
    {
      const int o_l = t >> 2;
      const int cc  = (t & 3) * 8;
      float4 v0 = *(const float4*)(W1 + (size_t)(o0 + o_l) * 256 + c0 + cc);
      float4 v1 = *(const float4*)(W1 + (size_t)(o0 + o_l) * 256 + c0 + cc + 4);
      wsh[cc + 0][o_l] = v0.x; wsh[cc + 1][o_l] = v0.y;
      wsh[cc + 2][o_l] = v0.z; wsh[cc + 3][o_l] = v0.w;
      wsh[cc + 4][o_l] = v1.x; wsh[cc + 5][o_l] = v1.y;
      wsh[cc + 6][o_l] = v1.z; wsh[cc + 7][o_l] = v1.w;
    }
    __syncthreads();
#pragma unroll 8
    for (int kk = 0; kk < 32; ++kk) {
      float xv[4], wv[8];
      *(float4*)&xv[0] = *(const float4*)&xs[kk][tx * 4];
      *(float4*)&wv[0] = *(const float4*)&wsh[kk][ty * 8];
      *(float4*)&wv[4] = *(const float4*)&wsh[kk][ty * 8 + 4];
#pragma unroll
      for (int i = 0; i < 4; ++i)
#pragma unroll
        for (int j = 0; j < 8; ++j) acc[i][j] = fmaf(xv[i], wv[j], acc[i][j]);
    }
    __syncthreads();
  }

#pragma unroll
  for (int j = 0; j < 8; ++j) {
    const int o = o0 + ty * 8 + j;
    const float bb = b1[o];
    float4 v;
    v.x = acc[0][j] + bb; v.y = acc[1][j] + bb;
    v.z = acc[2][j] + bb; v.w = acc[3][j] + bb;
    *(float4*)(f1 + ((size_t)(b * 256 + o)) * 16384 + pbase + tx * 4) = v;
  }
}

// ---------------------------------------------------------------------------
// Kernel 2: partial L1 distances, channel-major, NO LDS / NO BARRIERS.
// Block: 256 thr = 8 rows x 32 float4-cols; thread owns 4 px of row h0+r.
// Per channel: 3 direct global float4 loads (rows h-1,h,h+1; row h is an
// L1 hit for adjacent thread-rows), horizontal neighbors via __shfl
// (lane wrap-around positions are exactly the edge-clamped ones),
// accumulate |c-n| in 32 regs. End: 32 atomicAdds into dist[p][8].
// Grid: (16 htiles, 4 b, 8 c-chunks) = 512 blocks.
// ---------------------------------------------------------------------------
__global__ __launch_bounds__(256) void k_dist(const float* __restrict__ f1,
                                              float* __restrict__ dist)
{
  const int t    = threadIdx.x;
  const int r    = t >> 5, cq = t & 31;
  const int lane = t & 63;
  const int h0 = blockIdx.x * 8;
  const int b  = blockIdx.y;
  const int c0 = blockIdx.z * 32;
  const int h  = h0 + r;
  const int hu = h == 0 ? 0 : h - 1;
  const int hd = h == 127 ? 127 : h + 1;
  const int colo = cq * 4;
  const float* plane0 = f1 + ((size_t)(b * 256 + c0)) * 16384;

  float acc[4][8];
#pragma unroll
  for (int i = 0; i < 4; ++i)
#pragma unroll
    for (int k = 0; k < 8; ++k) acc[i][k] = 0.f;

#pragma unroll 4
  for (int cc = 0; cc < 32; ++cc) {
    const float* pl = plane0 + (size_t)cc * 16384;
    float4 vv[3];
    vv[0] = *(const float4*)(pl + hu * 128 + colo);
    vv[1] = *(const float4*)(pl + h  * 128 + colo);
    vv[2] = *(const float4*)(pl + hd * 128 + colo);
    float vals[3][6];
#pragma unroll
    for (int d = 0; d < 3; ++d) {
      const float lf = __shfl(vv[d].w, (lane + 63) & 63, 64);
      const float rg = __shfl(vv[d].x, (lane + 1) & 63, 64);
      vals[d][0] = (cq == 0)  ? vv[d].x : lf;
      vals[d][1] = vv[d].x; vals[d][2] = vv[d].y;
      vals[d][3] = vv[d].z; vals[d][4] = vv[d].w;
      vals[d][5] = (cq == 31) ? vv[d].w : rg;
    }
#pragma unroll
    for (int i = 0; i < 4; ++i) {
      const float cv = vals[1][i + 1];
      acc[i][0] += fabsf(cv - vals[0][i]);
      acc[i][1] += fabsf(cv - vals[0][i + 1]);
      acc[i][2] += fabsf(cv - vals[0][i + 2]);
      acc[i][3] += fabsf(cv - vals[1][i]);
      acc[i][4] += fabsf(cv - vals[1][i + 2]);
      acc[i][5] += fabsf(cv - vals[2][i]);
      acc[i][6] += fabsf(cv - vals[2][i + 1]);
      acc[i][7] += fabsf(cv - vals[2][i + 2]);
    }
  }

  const int p = (b << 14) + h * 128 + colo;
#pragma unroll
  for (int i = 0; i < 4; ++i)
#pragma unroll
    for (int k = 0; k < 8; ++k)
      atomicAdd(&dist[(size_t)(p + i) * 8 + k], acc[i][k]);
}

// ---------------------------------------------------------------------------
// Kernel 3: softmax(-r*dist) per pixel (regs), weighted aggregation +
// residual, write pre-BN channel-major, fused BN stats (wave butterfly ->
// 1 atomic pair per wave per channel). Same no-LDS/no-barrier stencil.
// ---------------------------------------------------------------------------
__global__ __launch_bounds__(256) void k_agg2(const float* __restrict__ f1,
                                              const float* __restrict__ x,
                                              const float* __restrict__ dist,
                                              const float* __restrict__ rp,
                                              float* __restrict__ bn_in,
                                              float* __restrict__ s1,
                                              float* __restrict__ s2)
{
  const int t    = threadIdx.x;
  const int r    = t >> 5, cq = t & 31;
  const int lane = t & 63;
  const int h0 = blockIdx.x * 8;
  const int b  = blockIdx.y;
  const int c0 = blockIdx.z * 32;
  const int h  = h0 + r;
  const int hu = h == 0 ? 0 : h - 1;
  const int hd = h == 127 ? 127 : h + 1;
  const int colo = cq * 4;
  const int p  = (b << 14) + h * 128 + colo;
  const float rv = rp[0];

  // softmax weights for this thread's 4 pixels
  float m[4][8];
#pragma unroll
  for (int i = 0; i < 4; ++i) {
    float4 d0 = *(const float4*)(dist + (size_t)(p + i) * 8);
    float4 d1 = *(const float4*)(dist + (size_t)(p + i) * 8 + 4);
    float lg[8] = {-rv * d0.x, -rv * d0.y, -rv * d0.z, -rv * d0.w,
                   -rv * d1.x, -rv * d1.y, -rv * d1.z, -rv * d1.w};
    float mx = lg[0];
#pragma unroll
    for (int k = 1; k < 8; ++k) mx = fmaxf(mx, lg[k]);
    float sm = 0.f;
#pragma unroll
    for (int k = 0; k < 8; ++k) { lg[k] = __expf(lg[k] - mx); sm += lg[k]; }
    const float inv = 1.f / sm;
#pragma unroll
    for (int k = 0; k < 8; ++k) m[i][k] = lg[k] * inv;
  }

  const float* plane0 = f1 + ((size_t)(b * 256 + c0)) * 16384;
#pragma unroll 2
  for (int cc = 0; cc < 32; ++cc) {
    const float* pl = plane0 + (size_t)cc * 16384;
    float4 vv[3];
    vv[0] = *(const float4*)(pl + hu * 128 + colo);
    vv[1] = *(const float4*)(pl + h  * 128 + colo);
    vv[2] = *(const float4*)(pl + hd * 128 + colo);
    float vals[3][6];
#pragma unroll
    for (int d = 0; d < 3; ++d) {
      const float lf = __shfl(vv[d].w, (lane + 63) & 63, 64);
      const float rg = __shfl(vv[d].x, (lane + 1) & 63, 64);
      vals[d][0] = (cq == 0)  ? vv[d].x : lf;
      vals[d][1] = vv[d].x; vals[d][2] = vv[d].y;
      vals[d][3] = vv[d].z; vals[d][4] = vv[d].w;
      vals[d][5] = (cq == 31) ? vv[d].w : rg;
    }

    const size_t chanoff = ((size_t)(b * 256 + c0 + cc)) * 16384 +
                           (size_t)h * 128 + colo;
    const float4 xv = *(const float4*)(x + chanoff);
    float o_[4] = {xv.x, xv.y, xv.z, xv.w};
#pragma unroll
    for (int i = 0; i < 4; ++i) {
      o_[i] = fmaf(m[i][0], vals[0][i],     o_[i]);
      o_[i] = fmaf(m[i][1], vals[0][i + 1], o_[i]);
      o_[i] = fmaf(m[i][2], vals[0][i + 2], o_[i]);
      o_[i] = fmaf(m[i][3], vals[1][i],     o_[i]);
      o_[i] = fmaf(m[i][4], vals[1][i + 2], o_[i]);
      o_[i] = fmaf(m[i][5], vals[2][i],     o_[i]);
      o_[i] = fmaf(m[i][6], vals[2][i + 1], o_[i]);
      o_[i] = fmaf(m[i][7], vals[2][i + 2], o_[i]);
    }
    float4 ov; ov.x = o_[0]; ov.y = o_[1]; ov.z = o_[2]; ov.w = o_[3];
    *(float4*)(bn_in + chanoff) = ov;

    // BN stats: wave butterfly, then one atomic pair per wave
    float s = o_[0] + o_[1] + o_[2] + o_[3];
    float q = o_[0] * o_[0] + o_[1] * o_[1] + o_[2] * o_[2] + o_[3] * o_[3];
#pragma unroll
    for (int msk = 1; msk < 64; msk <<= 1) {
      s += __shfl_xor(s, msk, 64);
      q += __shfl_xor(q, msk, 64);
    }
    if (lane == 0) {
      atomicAdd(&s1[c0 + cc], s);
      atomicAdd(&s2[c0 + cc], q);
    }
  }
}

// ---------------------------------------------------------------------------
// Kernel 4: per-channel BN folds: scale = gamma*rsqrt(var+eps),
//           shift = beta - mean*scale   (biased var, N = 65536)
// ---------------------------------------------------------------------------
__global__ void k_stats(const float* __restrict__ s1, const float* __restrict__ s2,
                        const float* __restrict__ gamma, const float* __restrict__ beta,
                        float* __restrict__ scale, float* __restrict__ shift)
{
  const int c = threadIdx.x;
  const float n = 65536.f;
  const float mean = s1[c] / n;
  const float var  = s2[c] / n - mean * mean;
  const float sc   = gamma[c] * rsqrtf(var + EPS_);
  scale[c] = sc;
  shift[c] = beta[c] - mean * sc;
}

// ---------------------------------------------------------------------------
// Kernel 5: elementwise BN affine + LeakyReLU (channel-major, no transpose).
// ---------------------------------------------------------------------------
__global__ __launch_bounds__(256) void k_apply(const float* __restrict__ bn_in,
                                               const float* __restrict__ scale,
                                               const float* __restrict__ shift,
                                               float* __restrict__ out)
{
  const int base = blockIdx.x * 1024 + threadIdx.x;   // float4 index
#pragma unroll
  for (int j = 0; j < 4; ++j) {
    const int idx = base + j * 256;
    const int c   = (idx >> 12) & 255;               // elem>>14 == idx>>12
    const float sc = scale[c], sh = shift[c];
    const float4 v = *(const float4*)(bn_in + (size_t)idx * 4);
    float4 o;
    float u;
    u = fmaf(v.x, sc, sh); o.x = u > 0.f ? u : 0.01f * u;
    u = fmaf(v.y, sc, sh); o.y = u > 0.f ? u : 0.01f * u;
    u = fmaf(v.z, sc, sh); o.z = u > 0.f ? u : 0.01f * u;
    u = fmaf(v.w, sc, sh); o.w = u > 0.f ? u : 0.01f * u;
    *(float4*)(out + (size_t)idx * 4) = o;
  }
}

// ---------------------------------------------------------------------------
// Workspace: f1 64MB | bn_in 64MB | dist 2MB | s1/s2/scale/shift 4KB
// ---------------------------------------------------------------------------
extern "C" void kernel_launch(void* const* d_in, const int* in_sizes, int n_in,
                              void* d_out, int out_size, void* d_ws, size_t ws_size,
                              hipStream_t stream)
{
  const float* x     = (const float*)d_in[0];
  const float* W1    = (const float*)d_in[1];
  const float* b1    = (const float*)d_in[2];
  const float* r     = (const float*)d_in[3];
  const float* gamma = (const float*)d_in[4];
  const float* beta  = (const float*)d_in[5];
  float* out = (float*)d_out;

  char* ws = (char*)d_ws;
  float* f1    = (float*)ws;                           // 64 MB
  float* bn_in = (float*)(ws + ((size_t)64 << 20));    // 64 MB
  float* dist  = (float*)(ws + ((size_t)128 << 20));   // 2 MB
  float* s1    = dist + 524288;
  float* s2    = s1 + 256;
  float* scale = s1 + 512;
  float* shift = s1 + 768;

  // zero dist + s1 + s2 (contiguous): 2 MB + 2 KB
  hipMemsetAsync(dist, 0, 524288 * sizeof(float) + 512 * sizeof(float), stream);

  k_gemm <<<dim3(128, 4, 4), 256, 0, stream>>>(x, W1, b1, f1);
  k_dist <<<dim3(16, 4, 8),  256, 0, stream>>>(f1, dist);
  k_agg2 <<<dim3(16, 4, 8),  256, 0, stream>>>(f1, x, dist, r, bn_in, s1, s2);
  k_stats<<<dim3(1),         256, 0, stream>>>(s1, s2, gamma, beta, scale, shift);
  k_apply<<<dim3(4096),      256, 0, stream>>>(bn_in, scale, shift, out);
}

// Round 4
// 383.554 us; speedup vs baseline: 1.5015x; 1.4699x over previous
//
#include <hip/hip_runtime.h>
#include <cstddef>

// Problem: B=4, C=256, H=W=128, HW=16384, NPIX=65536
#define EPS_ 1e-5f

// ---------------------------------------------------------------------------
// Kernel 1: per-batch GEMM, CHANNEL-major output:
//   f1[((b*256 + o) * 16384) + p] = sum_c x[b,c,p] * W1[o,c] + b1[o]
// ---------------------------------------------------------------------------
__global__ __launch_bounds__(256) void k_gemm(const float* __restrict__ x,
                                              const float* __restrict__ W1,
                                              const float* __restrict__ b1,
                                              float* __restrict__ f1)
{
  __shared__ float xs[32][128];   // [k][p]
  __shared__ float wsh[32][68];   // [k][o]
  const int t  = threadIdx.x;
  const int tx = t & 31, ty = t >> 5;
  const int pbase = blockIdx.x * 128;
  const int o0    = blockIdx.y * 64;
  const int b     = blockIdx.z;
  const float* xb = x + (size_t)b * 256 * 16384;

  float acc[4][8];
#pragma unroll
  for (int i = 0; i < 4; ++i)
#pragma unroll
    for (int j = 0; j < 8; ++j) acc[i][j] = 0.f;

  for (int c0 = 0; c0 < 256; c0 += 32) {
    {
      const int row = t >> 3;
      const int f4  = t & 7;
#pragma unroll
      for (int jj = 0; jj < 4; ++jj) {
        const int col = (f4 + jj * 8) * 4;
        *(float4*)&xs[row][col] =
            *(const float4*)(xb + (size_t)(c0 + row) * 16384 + pbase + col);
      }
    }
    {
      const int o_l = t >> 2;
      const int cc  = (t & 3) * 8;
      float4 v0 = *(const float4*)(W1 + (size_t)(o0 + o_l) * 256 + c0 + cc);
      float4 v1 = *(const float4*)(W1 + (size_t)(o0 + o_l) * 256 + c0 + cc + 4);
      wsh[cc + 0][o_l] = v0.x; wsh[cc + 1][o_l] = v0.y;
      wsh[cc + 2][o_l] = v0.z; wsh[cc + 3][o_l] = v0.w;
      wsh[cc + 4][o_l] = v1.x; wsh[cc + 5][o_l] = v1.y;
      wsh[cc + 6][o_l] = v1.z; wsh[cc + 7][o_l] = v1.w;
    }
    __syncthreads();
#pragma unroll 8
    for (int kk = 0; kk < 32; ++kk) {
      float xv[4], wv[8];
      *(float4*)&xv[0] = *(const float4*)&xs[kk][tx * 4];
      *(float4*)&wv[0] = *(const float4*)&wsh[kk][ty * 8];
      *(float4*)&wv[4] = *(const float4*)&wsh[kk][ty * 8 + 4];
#pragma unroll
      for (int i = 0; i < 4; ++i)
#pragma unroll
        for (int j = 0; j < 8; ++j) acc[i][j] = fmaf(xv[i], wv[j], acc[i][j]);
    }
    __syncthreads();
  }

#pragma unroll
  for (int j = 0; j < 8; ++j) {
    const int o = o0 + ty * 8 + j;
    const float bb = b1[o];
    float4 v;
    v.x = acc[0][j] + bb; v.y = acc[1][j] + bb;
    v.z = acc[2][j] + bb; v.w = acc[3][j] + bb;
    *(float4*)(f1 + ((size_t)(b * 256 + o)) * 16384 + pbase + tx * 4) = v;
  }
}

// ---------------------------------------------------------------------------
// Kernel 2: partial L1 distances. NO atomics: each c-chunk block streams its
// partials to a private slice dist_part[chunk][k][p] (transposed in regs so
// consecutive lanes store consecutive float4 -> fully coalesced).
// Grid: (16 htiles, 4 b, 8 c-chunks) = 512 blocks, 256 thr (8 rows x 32 f4).
// ---------------------------------------------------------------------------
__global__ __launch_bounds__(256) void k_dist(const float* __restrict__ f1,
                                              float* __restrict__ dist_part)
{
  const int t    = threadIdx.x;
  const int r    = t >> 5, cq = t & 31;
  const int lane = t & 63;
  const int h0 = blockIdx.x * 8;
  const int b  = blockIdx.y;
  const int c0 = blockIdx.z * 32;
  const int h  = h0 + r;
  const int hu = h == 0 ? 0 : h - 1;
  const int hd = h == 127 ? 127 : h + 1;
  const int colo = cq * 4;
  const float* plane0 = f1 + ((size_t)(b * 256 + c0)) * 16384;

  float acc[4][8];
#pragma unroll
  for (int i = 0; i < 4; ++i)
#pragma unroll
    for (int k = 0; k < 8; ++k) acc[i][k] = 0.f;

#pragma unroll 4
  for (int cc = 0; cc < 32; ++cc) {
    const float* pl = plane0 + (size_t)cc * 16384;
    float4 vv[3];
    vv[0] = *(const float4*)(pl + hu * 128 + colo);
    vv[1] = *(const float4*)(pl + h  * 128 + colo);
    vv[2] = *(const float4*)(pl + hd * 128 + colo);
    float vals[3][6];
#pragma unroll
    for (int d = 0; d < 3; ++d) {
      const float lf = __shfl(vv[d].w, (lane + 63) & 63, 64);
      const float rg = __shfl(vv[d].x, (lane + 1) & 63, 64);
      vals[d][0] = (cq == 0)  ? vv[d].x : lf;
      vals[d][1] = vv[d].x; vals[d][2] = vv[d].y;
      vals[d][3] = vv[d].z; vals[d][4] = vv[d].w;
      vals[d][5] = (cq == 31) ? vv[d].w : rg;
    }
#pragma unroll
    for (int i = 0; i < 4; ++i) {
      const float cv = vals[1][i + 1];
      acc[i][0] += fabsf(cv - vals[0][i]);
      acc[i][1] += fabsf(cv - vals[0][i + 1]);
      acc[i][2] += fabsf(cv - vals[0][i + 2]);
      acc[i][3] += fabsf(cv - vals[1][i]);
      acc[i][4] += fabsf(cv - vals[1][i + 2]);
      acc[i][5] += fabsf(cv - vals[2][i]);
      acc[i][6] += fabsf(cv - vals[2][i + 1]);
      acc[i][7] += fabsf(cv - vals[2][i + 2]);
    }
  }

  // dist_part[chunk][k][p]: per k, float4 over the 4 pixels -> coalesced
  const int p = (b << 14) + h * 128 + colo;
  float* base = dist_part + ((size_t)blockIdx.z << 19);   // chunk * 8*65536
#pragma unroll
  for (int k = 0; k < 8; ++k) {
    float4 v; v.x = acc[0][k]; v.y = acc[1][k]; v.z = acc[2][k]; v.w = acc[3][k];
    *(float4*)(base + (size_t)k * 65536 + p) = v;
  }
}

// ---------------------------------------------------------------------------
// Kernel 2b: sum the 8 chunk-partials per pixel, softmax once, write
// wts[p][8] (2 MB). 1 px/thread, coalesced scalar reads.
// ---------------------------------------------------------------------------
__global__ __launch_bounds__(256) void k_soft(const float* __restrict__ dist_part,
                                              const float* __restrict__ rp,
                                              float* __restrict__ wts)
{
  const int p = blockIdx.x * 256 + threadIdx.x;
  const float rv = rp[0];
  float d[8];
#pragma unroll
  for (int k = 0; k < 8; ++k) d[k] = 0.f;
  for (int ch = 0; ch < 8; ++ch) {
    const float* base = dist_part + ((size_t)ch << 19);
#pragma unroll
    for (int k = 0; k < 8; ++k) d[k] += base[(size_t)k * 65536 + p];
  }
  float lg[8];
  float mx = -rv * d[0];
#pragma unroll
  for (int k = 1; k < 8; ++k) mx = fmaxf(mx, -rv * d[k]);
  float sm = 0.f;
#pragma unroll
  for (int k = 0; k < 8; ++k) { lg[k] = __expf(fmaf(-rv, d[k], -mx)); sm += lg[k]; }
  const float inv = 1.f / sm;
  float4 w0, w1;
  w0.x = lg[0] * inv; w0.y = lg[1] * inv; w0.z = lg[2] * inv; w0.w = lg[3] * inv;
  w1.x = lg[4] * inv; w1.y = lg[5] * inv; w1.z = lg[6] * inv; w1.w = lg[7] * inv;
  *(float4*)(wts + (size_t)p * 8)     = w0;
  *(float4*)(wts + (size_t)p * 8 + 4) = w1;
}

// ---------------------------------------------------------------------------
// Kernel 3: weighted aggregation + residual using precomputed wts, write
// pre-BN channel-major, fused BN stats (butterfly -> 1 atomic pair/wave/ch).
// ---------------------------------------------------------------------------
__global__ __launch_bounds__(256) void k_agg2(const float* __restrict__ f1,
                                              const float* __restrict__ x,
                                              const float* __restrict__ wts,
                                              float* __restrict__ bn_in,
                                              float* __restrict__ s1,
                                              float* __restrict__ s2)
{
  const int t    = threadIdx.x;
  const int r    = t >> 5, cq = t & 31;
  const int lane = t & 63;
  const int h0 = blockIdx.x * 8;
  const int b  = blockIdx.y;
  const int c0 = blockIdx.z * 32;
  const int h  = h0 + r;
  const int hu = h == 0 ? 0 : h - 1;
  const int hd = h == 127 ? 127 : h + 1;
  const int colo = cq * 4;
  const int p  = (b << 14) + h * 128 + colo;

  float m[4][8];
#pragma unroll
  for (int i = 0; i < 4; ++i) {
    float4 w0 = *(const float4*)(wts + (size_t)(p + i) * 8);
    float4 w1 = *(const float4*)(wts + (size_t)(p + i) * 8 + 4);
    m[i][0] = w0.x; m[i][1] = w0.y; m[i][2] = w0.z; m[i][3] = w0.w;
    m[i][4] = w1.x; m[i][5] = w1.y; m[i][6] = w1.z; m[i][7] = w1.w;
  }

  const float* plane0 = f1 + ((size_t)(b * 256 + c0)) * 16384;
#pragma unroll 2
  for (int cc = 0; cc < 32; ++cc) {
    const float* pl = plane0 + (size_t)cc * 16384;
    float4 vv[3];
    vv[0] = *(const float4*)(pl + hu * 128 + colo);
    vv[1] = *(const float4*)(pl + h  * 128 + colo);
    vv[2] = *(const float4*)(pl + hd * 128 + colo);
    float vals[3][6];
#pragma unroll
    for (int d = 0; d < 3; ++d) {
      const float lf = __shfl(vv[d].w, (lane + 63) & 63, 64);
      const float rg = __shfl(vv[d].x, (lane + 1) & 63, 64);
      vals[d][0] = (cq == 0)  ? vv[d].x : lf;
      vals[d][1] = vv[d].x; vals[d][2] = vv[d].y;
      vals[d][3] = vv[d].z; vals[d][4] = vv[d].w;
      vals[d][5] = (cq == 31) ? vv[d].w : rg;
    }

    const size_t chanoff = ((size_t)(b * 256 + c0 + cc)) * 16384 +
                           (size_t)h * 128 + colo;
    const float4 xv = *(const float4*)(x + chanoff);
    float o_[4] = {xv.x, xv.y, xv.z, xv.w};
#pragma unroll
    for (int i = 0; i < 4; ++i) {
      o_[i] = fmaf(m[i][0], vals[0][i],     o_[i]);
      o_[i] = fmaf(m[i][1], vals[0][i + 1], o_[i]);
      o_[i] = fmaf(m[i][2], vals[0][i + 2], o_[i]);
      o_[i] = fmaf(m[i][3], vals[1][i],     o_[i]);
      o_[i] = fmaf(m[i][4], vals[1][i + 2], o_[i]);
      o_[i] = fmaf(m[i][5], vals[2][i],     o_[i]);
      o_[i] = fmaf(m[i][6], vals[2][i + 1], o_[i]);
      o_[i] = fmaf(m[i][7], vals[2][i + 2], o_[i]);
    }
    float4 ov; ov.x = o_[0]; ov.y = o_[1]; ov.z = o_[2]; ov.w = o_[3];
    *(float4*)(bn_in + chanoff) = ov;

    float s = o_[0] + o_[1] + o_[2] + o_[3];
    float q = o_[0] * o_[0] + o_[1] * o_[1] + o_[2] * o_[2] + o_[3] * o_[3];
#pragma unroll
    for (int msk = 1; msk < 64; msk <<= 1) {
      s += __shfl_xor(s, msk, 64);
      q += __shfl_xor(q, msk, 64);
    }
    if (lane == 0) {
      atomicAdd(&s1[c0 + cc], s);
      atomicAdd(&s2[c0 + cc], q);
    }
  }
}

// ---------------------------------------------------------------------------
// Kernel 4: BN folds
// ---------------------------------------------------------------------------
__global__ void k_stats(const float* __restrict__ s1, const float* __restrict__ s2,
                        const float* __restrict__ gamma, const float* __restrict__ beta,
                        float* __restrict__ scale, float* __restrict__ shift)
{
  const int c = threadIdx.x;
  const float n = 65536.f;
  const float mean = s1[c] / n;
  const float var  = s2[c] / n - mean * mean;
  const float sc   = gamma[c] * rsqrtf(var + EPS_);
  scale[c] = sc;
  shift[c] = beta[c] - mean * sc;
}

// ---------------------------------------------------------------------------
// Kernel 5: elementwise BN affine + LeakyReLU
// ---------------------------------------------------------------------------
__global__ __launch_bounds__(256) void k_apply(const float* __restrict__ bn_in,
                                               const float* __restrict__ scale,
                                               const float* __restrict__ shift,
                                               float* __restrict__ out)
{
  const int base = blockIdx.x * 1024 + threadIdx.x;   // float4 index
#pragma unroll
  for (int j = 0; j < 4; ++j) {
    const int idx = base + j * 256;
    const int c   = (idx >> 12) & 255;
    const float sc = scale[c], sh = shift[c];
    const float4 v = *(const float4*)(bn_in + (size_t)idx * 4);
    float4 o;
    float u;
    u = fmaf(v.x, sc, sh); o.x = u > 0.f ? u : 0.01f * u;
    u = fmaf(v.y, sc, sh); o.y = u > 0.f ? u : 0.01f * u;
    u = fmaf(v.z, sc, sh); o.z = u > 0.f ? u : 0.01f * u;
    u = fmaf(v.w, sc, sh); o.w = u > 0.f ? u : 0.01f * u;
    *(float4*)(out + (size_t)idx * 4) = o;
  }
}

// ---------------------------------------------------------------------------
// Workspace: f1 64MB | bn_in 64MB (dist_part 16MB aliases its head; dead
// before k_agg2 writes) | wts 2MB | s1/s2/scale/shift 4KB.  Total ~130MB.
// ---------------------------------------------------------------------------
extern "C" void kernel_launch(void* const* d_in, const int* in_sizes, int n_in,
                              void* d_out, int out_size, void* d_ws, size_t ws_size,
                              hipStream_t stream)
{
  const float* x     = (const float*)d_in[0];
  const float* W1    = (const float*)d_in[1];
  const float* b1    = (const float*)d_in[2];
  const float* r     = (const float*)d_in[3];
  const float* gamma = (const float*)d_in[4];
  const float* beta  = (const float*)d_in[5];
  float* out = (float*)d_out;

  char* ws = (char*)d_ws;
  float* f1        = (float*)ws;                           // 64 MB
  float* bn_in     = (float*)(ws + ((size_t)64 << 20));    // 64 MB
  float* dist_part = bn_in;                                // 16 MB alias (dead before bn_in written)
  float* wts       = (float*)(ws + ((size_t)128 << 20));   // 2 MB
  float* s1        = wts + 524288;
  float* s2        = s1 + 256;
  float* scale     = s1 + 512;
  float* shift     = s1 + 768;

  hipMemsetAsync(s1, 0, 512 * sizeof(float), stream);

  k_gemm <<<dim3(128, 4, 4), 256, 0, stream>>>(x, W1, b1, f1);
  k_dist <<<dim3(16, 4, 8),  256, 0, stream>>>(f1, dist_part);
  k_soft <<<dim3(256),       256, 0, stream>>>(dist_part, r, wts);
  k_agg2 <<<dim3(16, 4, 8),  256, 0, stream>>>(f1, x, wts, bn_in, s1, s2);
  k_stats<<<dim3(1),         256, 0, stream>>>(s1, s2, gamma, beta, scale, shift);
  k_apply<<<dim3(4096),      256, 0, stream>>>(bn_in, scale, shift, out);
}